// Round 2
// baseline (816.194 us; speedup 1.0000x reference)
//
#include <hip/hip_runtime.h>
#include <hip/hip_bf16.h>

typedef __bf16 bf16_t;
typedef __attribute__((ext_vector_type(8))) __bf16 bf16x8;
typedef __attribute__((ext_vector_type(4))) float f32x4;

// Direct HBM->LDS DMA, 16B per lane. LDS dest = wave-uniform base + lane*16.
#define GLOAD_LDS16(gp, lp)                                                    \
  __builtin_amdgcn_global_load_lds(                                            \
      (const __attribute__((address_space(1))) void*)(gp),                     \
      (__attribute__((address_space(3))) void*)(lp), 16, 0, 0)

// ---------------- prep kernels (tiny) ----------------
// Wvp[i][p] = sum_d Wv[i][d] * Wp[d][p]   (512 x 256)
// bvp[i]    = sum_d Wv[i][d] * bp[d] + bv[i]
__global__ void prep_wvp(const float* __restrict__ Wv, const float* __restrict__ Wp,
                         const float* __restrict__ bp, const float* __restrict__ bv,
                         float* __restrict__ Wvp, float* __restrict__ bvp) {
  const int i = blockIdx.x;
  const int j = threadIdx.x;
  float a = 0.f;
  for (int d = 0; d < 512; ++d) a += Wv[i * 512 + d] * Wp[d * 256 + j];
  Wvp[i * 256 + j] = a;
  if (j == 0) {
    float b = 0.f;
    for (int d = 0; d < 512; ++d) b += Wv[i * 512 + d] * bp[d];
    bvp[i] = b + bv[i];
  }
}

// Wc[o][p] = sum_i Wo[o][i] * Wvp[i][p]  -> bf16 (512 x 256)
// bcomb[o] = sum_i Wo[o][i] * bvp[i] + bo[o]
__global__ void prep_wc(const float* __restrict__ Wo, const float* __restrict__ bo,
                        const float* __restrict__ Wvp, const float* __restrict__ bvp,
                        bf16_t* __restrict__ Wc, float* __restrict__ bcomb) {
  const int o = blockIdx.x;
  const int j = threadIdx.x;
  float a = 0.f;
  for (int i = 0; i < 512; ++i) a += Wo[o * 512 + i] * Wvp[i * 256 + j];
  Wc[o * 256 + j] = (bf16_t)a;
  if (j == 0) {
    float b = 0.f;
    for (int i = 0; i < 512; ++i) b += Wo[o * 512 + i] * bvp[i];
    bcomb[o] = b + bo[o];
  }
}

// cast W1 (524288) then W2 (524288) to bf16
__global__ void prep_cast(const float* __restrict__ W1, const float* __restrict__ W2,
                          bf16_t* __restrict__ W1b, bf16_t* __restrict__ W2b) {
  const int idx = (blockIdx.x * 256 + threadIdx.x) * 8;
  const float* s;
  bf16_t* d;
  if (idx < 524288) { s = W1 + idx; d = W1b + idx; }
  else { s = W2 + (idx - 524288); d = W2b + (idx - 524288); }
  float4 u0 = *(const float4*)s;
  float4 u1 = *(const float4*)(s + 4);
  bf16x8 v;
  v[0] = (bf16_t)u0.x; v[1] = (bf16_t)u0.y; v[2] = (bf16_t)u0.z; v[3] = (bf16_t)u0.w;
  v[4] = (bf16_t)u1.x; v[5] = (bf16_t)u1.y; v[6] = (bf16_t)u1.z; v[7] = (bf16_t)u1.w;
  *(bf16x8*)d = v;
}

// ---------------- fused GEMM ----------------
// C[m][n] = sum_k A[m][k] * Bw[n][k]  (Bw row-major N x K, i.e. X @ W.T)
// Block tile: 64 rows x 512 cols, BK=32, 256 threads (4 waves),
// wave w owns cols [128w, 128w+128), all 64 rows -> 4x8 tiles of 16x16.
//
// LDS layout (both A and B tiles): 16-row "windows" of 1 KiB. Within a window,
// 16B slot s = r*4 + (q ^ ((r>>1)&3)) holds k-chunk q (8 bf16) of row r.
//   - staged by global_load_lds with a PRE-SWIZZLED per-lane global source
//     (linear lane->slot dest, rule: both-sides-or-neither), 64B-coalesced per
//     4 lanes on the global side.
//   - ds_read_b128 of fragment (row=16*i+r, chunk q) at win*1024 + r*64 + qs*16
//     hits 8 distinct bank-quads per 8 lanes -> only 2-way aliasing (free).
//
// EPI 0: + bias + cell residual, LayerNorm(g,b) -> bf16 out (stride 512)
// EPI 1: + bias, exact GELU -> bf16 out (stride 1024)
// EPI 2: + bias + bf16 x residual, LayerNorm -> fp32 out (stride 512)
template <int K, int EPI>
__global__ __launch_bounds__(256, 2) void gemm_fused(
    const float* __restrict__ Af32, const bf16_t* __restrict__ Abf, const int lda,
    const bf16_t* __restrict__ Bw,
    const float* __restrict__ bias,
    const float* __restrict__ cellRes,
    const bf16_t* __restrict__ xRes,
    const float* __restrict__ gamma, const float* __restrict__ beta,
    bf16_t* __restrict__ outBf, float* __restrict__ outF32) {

  __shared__ __align__(16) bf16_t lA[64 * 32];    // 4 KiB, 4 windows
  __shared__ __align__(16) bf16_t lB[512 * 32];   // 32 KiB, 32 windows
  __shared__ float rs[4][64];
  __shared__ float rss[4][64];

  const int t = threadIdx.x;
  const int m0 = blockIdx.x * 64;
  const int n0 = blockIdx.y * 512;  // only nonzero for EPI==1 (N=1024)
  const int lane = t & 63;
  const int w = t >> 6;
  const int r = lane & 15;
  const int q = lane >> 4;
  const int qs = q ^ ((r >> 1) & 3);

  // LDS read bases (bf16-element units): window*512 + r*32 + qs*8
  const int aRd = r * 32 + qs * 8;
  const int bRd = w * 4096 + r * 32 + qs * 8;  // window 8w+j -> + j*512

  // staging source mapping: lane l -> (row_in_window = l>>2, chunk = (l&3)^((l>>3)&3))
  const int srow = lane >> 2;
  const int sq = (lane & 3) ^ ((lane >> 3) & 3);

  f32x4 acc[4][8];
#pragma unroll
  for (int i = 0; i < 4; ++i)
#pragma unroll
    for (int j = 0; j < 8; ++j)
#pragma unroll
      for (int p = 0; p < 4; ++p) acc[i][j][p] = 0.f;

  // EPI 0 A-staging (fp32 -> bf16 via regs): thread t handles row=t>>2, chunk c=t&3,
  // writes to the swizzled slot of window t>>6 (conflict-free ds_write_b128).
  int aWr = 0;
  if constexpr (EPI == 0) {
    const int arow = t >> 2;
    const int c = t & 3;
    const int rr = arow & 15;
    aWr = (arow >> 4) * 512 + (rr * 4 + (c ^ ((rr >> 1) & 3))) * 8;
  }

  for (int k0 = 0; k0 < K; k0 += 32) {
    // ---- stage B tile (512 x 32): 8 DMA issues per wave ----
#pragma unroll
    for (int i = 0; i < 8; ++i) {
      const bf16_t* gp = Bw + (size_t)(n0 + 64 * i + 16 * w + srow) * K + (k0 + sq * 8);
      GLOAD_LDS16(gp, &lB[(i * 4 + w) * 512]);
    }
    // ---- stage A tile (64 x 32) ----
    if constexpr (EPI == 0) {
      const float* src = Af32 + (size_t)(m0 + (t >> 2)) * lda + (k0 + (t & 3) * 8);
      float4 u0 = *(const float4*)src;
      float4 u1 = *(const float4*)(src + 4);
      bf16x8 v;
      v[0] = (bf16_t)u0.x; v[1] = (bf16_t)u0.y; v[2] = (bf16_t)u0.z; v[3] = (bf16_t)u0.w;
      v[4] = (bf16_t)u1.x; v[5] = (bf16_t)u1.y; v[6] = (bf16_t)u1.z; v[7] = (bf16_t)u1.w;
      *(bf16x8*)&lA[aWr] = v;
    } else {
      const bf16_t* gp = Abf + (size_t)(m0 + 16 * w + srow) * lda + (k0 + sq * 8);
      GLOAD_LDS16(gp, &lA[w * 512]);
    }
    __syncthreads();
    // ---- MFMA ----
    bf16x8 af[4];
#pragma unroll
    for (int i = 0; i < 4; ++i) af[i] = *(const bf16x8*)&lA[i * 512 + aRd];
#pragma unroll
    for (int j = 0; j < 8; ++j) {
      bf16x8 bfv = *(const bf16x8*)&lB[j * 512 + bRd];
#pragma unroll
      for (int i = 0; i < 4; ++i)
        acc[i][j] = __builtin_amdgcn_mfma_f32_16x16x32_bf16(af[i], bfv, acc[i][j], 0, 0, 0);
    }
    __syncthreads();
  }

  if constexpr (EPI == 1) {
#pragma unroll
    for (int j = 0; j < 8; ++j) {
      const int colg = n0 + 128 * w + 16 * j + r;
      const float bb = bias[colg];
#pragma unroll
      for (int i = 0; i < 4; ++i)
#pragma unroll
        for (int p = 0; p < 4; ++p) {
          const int rowg = m0 + 16 * i + 4 * q + p;
          float v = acc[i][j][p] + bb;
          float g = 0.5f * v * (1.0f + erff(v * 0.70710678118654752f));
          outBf[(size_t)rowg * 1024 + colg] = (bf16_t)g;
        }
    }
  } else {
    float s[4][4], ss[4][4];
#pragma unroll
    for (int i = 0; i < 4; ++i)
#pragma unroll
      for (int p = 0; p < 4; ++p) { s[i][p] = 0.f; ss[i][p] = 0.f; }

#pragma unroll
    for (int j = 0; j < 8; ++j) {
      const int col = 128 * w + 16 * j + r;
      const float bb = bias[col];
#pragma unroll
      for (int i = 0; i < 4; ++i)
#pragma unroll
        for (int p = 0; p < 4; ++p) {
          const int rowg = m0 + 16 * i + 4 * q + p;
          float v = acc[i][j][p] + bb;
          if constexpr (EPI == 0) v += cellRes[(size_t)rowg * 512 + col];
          else                    v += (float)xRes[(size_t)rowg * 512 + col];
          acc[i][j][p] = v;
          s[i][p] += v;
          ss[i][p] += v * v;
        }
    }
    // quad (16-lane) butterfly reduce over r
#pragma unroll
    for (int m = 1; m <= 8; m <<= 1) {
#pragma unroll
      for (int i = 0; i < 4; ++i)
#pragma unroll
        for (int p = 0; p < 4; ++p) {
          s[i][p] += __shfl_xor(s[i][p], m);
          ss[i][p] += __shfl_xor(ss[i][p], m);
        }
    }
    if (r == 0) {
#pragma unroll
      for (int i = 0; i < 4; ++i)
#pragma unroll
        for (int p = 0; p < 4; ++p) {
          rs[w][16 * i + 4 * q + p] = s[i][p];
          rss[w][16 * i + 4 * q + p] = ss[i][p];
        }
    }
    __syncthreads();
    float mu[4][4], inv[4][4];
#pragma unroll
    for (int i = 0; i < 4; ++i)
#pragma unroll
      for (int p = 0; p < 4; ++p) {
        const int rl = 16 * i + 4 * q + p;
        float tS = rs[0][rl] + rs[1][rl] + rs[2][rl] + rs[3][rl];
        float tQ = rss[0][rl] + rss[1][rl] + rss[2][rl] + rss[3][rl];
        float m_ = tS * (1.0f / 512.0f);
        float v_ = tQ * (1.0f / 512.0f) - m_ * m_;
        mu[i][p] = m_;
        inv[i][p] = rsqrtf(v_ + 1e-5f);
      }
#pragma unroll
    for (int j = 0; j < 8; ++j) {
      const int col = 128 * w + 16 * j + r;
      const float ga = gamma[col], be = beta[col];
#pragma unroll
      for (int i = 0; i < 4; ++i)
#pragma unroll
        for (int p = 0; p < 4; ++p) {
          const int rowg = m0 + 16 * i + 4 * q + p;
          float v = (acc[i][j][p] - mu[i][p]) * inv[i][p] * ga + be;
          if constexpr (EPI == 0) outBf[(size_t)rowg * 512 + col] = (bf16_t)v;
          else                    outF32[(size_t)rowg * 512 + col] = v;
        }
    }
  }
}

extern "C" void kernel_launch(void* const* d_in, const int* in_sizes, int n_in,
                              void* d_out, int out_size, void* d_ws, size_t ws_size,
                              hipStream_t stream) {
  const float* cell = (const float*)d_in[0];
  const float* pert = (const float*)d_in[1];
  const float* Wp   = (const float*)d_in[2];
  const float* bp   = (const float*)d_in[3];
  // d_in[4..7] = Wq,bq,Wk,bk: dead (softmax over a single key == 1 -> attn = v)
  const float* Wv   = (const float*)d_in[8];
  const float* bv   = (const float*)d_in[9];
  const float* Wo   = (const float*)d_in[10];
  const float* bo   = (const float*)d_in[11];
  const float* g1   = (const float*)d_in[12];
  const float* be1  = (const float*)d_in[13];
  const float* g2   = (const float*)d_in[14];
  const float* be2  = (const float*)d_in[15];
  const float* W1   = (const float*)d_in[16];
  const float* b1   = (const float*)d_in[17];
  const float* W2   = (const float*)d_in[18];
  const float* b2   = (const float*)d_in[19];

  char* ws = (char*)d_ws;
  float*  Wvp   = (float*)(ws + 0);          // 512*256*4   = 524288
  float*  bvp   = (float*)(ws + 524288);     // 512*4 (pad) = 2048
  float*  bcomb = (float*)(ws + 526336);     // 512*4 (pad) = 2048
  bf16_t* Wc    = (bf16_t*)(ws + 528384);    // 512*256*2   = 262144
  bf16_t* W1b   = (bf16_t*)(ws + 790528);    // 1024*512*2  = 1048576
  bf16_t* W2b   = (bf16_t*)(ws + 1839104);   // 512*1024*2  = 1048576
  bf16_t* xws   = (bf16_t*)(ws + 2887680);   // 65536*512*2 = 67108864
  bf16_t* hws   = (bf16_t*)(ws + 69996544);  // 65536*1024*2 = 134217728
  (void)in_sizes; (void)n_in; (void)out_size; (void)ws_size;

  prep_wvp<<<512, 256, 0, stream>>>(Wv, Wp, bp, bv, Wvp, bvp);
  prep_wc<<<512, 256, 0, stream>>>(Wo, bo, Wvp, bvp, Wc, bcomb);
  prep_cast<<<512, 256, 0, stream>>>(W1, W2, W1b, W2b);

  // G1: attn (pert @ Wc.T + bcomb) + cell residual + LN1 -> x bf16
  gemm_fused<256, 0><<<dim3(1024, 1), 256, 0, stream>>>(
      pert, nullptr, 256, Wc, bcomb, cell, nullptr, g1, be1, xws, nullptr);
  // G2: h = gelu(x @ W1.T + b1) -> bf16
  gemm_fused<512, 1><<<dim3(1024, 2), 256, 0, stream>>>(
      nullptr, xws, 512, W1b, b1, nullptr, nullptr, nullptr, nullptr, hws, nullptr);
  // G3: out = LN2(x + h @ W2.T + b2) -> fp32
  gemm_fused<1024, 2><<<dim3(1024, 1), 256, 0, stream>>>(
      nullptr, hws, 1024, W2b, b2, nullptr, xws, g2, be2, nullptr, (float*)d_out);
}

// Round 3
// 750.548 us; speedup vs baseline: 1.0875x; 1.0875x over previous
//
#include <hip/hip_runtime.h>
#include <hip/hip_bf16.h>

typedef __bf16 bf16_t;
typedef __attribute__((ext_vector_type(8))) __bf16 bf16x8;
typedef __attribute__((ext_vector_type(4))) float f32x4;

// Direct HBM->LDS DMA, 16B per lane. LDS dest = wave-uniform base + lane*16.
#define GLOAD_LDS16(gp, lp)                                                    \
  __builtin_amdgcn_global_load_lds(                                            \
      (const __attribute__((address_space(1))) void*)(gp),                     \
      (__attribute__((address_space(3))) void*)(lp), 16, 0, 0)

// ---------------- prep kernels (tiny) ----------------
// Wvp[i][p] = sum_d Wv[i][d] * Wp[d][p]   (512 x 256)
// bvp[i]    = sum_d Wv[i][d] * bp[d] + bv[i]
__global__ void prep_wvp(const float* __restrict__ Wv, const float* __restrict__ Wp,
                         const float* __restrict__ bp, const float* __restrict__ bv,
                         float* __restrict__ Wvp, float* __restrict__ bvp) {
  const int i = blockIdx.x;
  const int j = threadIdx.x;
  float a = 0.f;
  for (int d = 0; d < 512; ++d) a += Wv[i * 512 + d] * Wp[d * 256 + j];
  Wvp[i * 256 + j] = a;
  if (j == 0) {
    float b = 0.f;
    for (int d = 0; d < 512; ++d) b += Wv[i * 512 + d] * bp[d];
    bvp[i] = b + bv[i];
  }
}

// Wc[o][p] = sum_i Wo[o][i] * Wvp[i][p]  -> bf16 (512 x 256)
// bcomb[o] = sum_i Wo[o][i] * bvp[i] + bo[o]
__global__ void prep_wc(const float* __restrict__ Wo, const float* __restrict__ bo,
                        const float* __restrict__ Wvp, const float* __restrict__ bvp,
                        bf16_t* __restrict__ Wc, float* __restrict__ bcomb) {
  const int o = blockIdx.x;
  const int j = threadIdx.x;
  float a = 0.f;
  for (int i = 0; i < 512; ++i) a += Wo[o * 512 + i] * Wvp[i * 256 + j];
  Wc[o * 256 + j] = (bf16_t)a;
  if (j == 0) {
    float b = 0.f;
    for (int i = 0; i < 512; ++i) b += Wo[o * 512 + i] * bvp[i];
    bcomb[o] = b + bo[o];
  }
}

// cast W1 (524288) then W2 (524288) to bf16
__global__ void prep_cast(const float* __restrict__ W1, const float* __restrict__ W2,
                          bf16_t* __restrict__ W1b, bf16_t* __restrict__ W2b) {
  const int idx = (blockIdx.x * 256 + threadIdx.x) * 8;
  const float* s;
  bf16_t* d;
  if (idx < 524288) { s = W1 + idx; d = W1b + idx; }
  else { s = W2 + (idx - 524288); d = W2b + (idx - 524288); }
  float4 u0 = *(const float4*)s;
  float4 u1 = *(const float4*)(s + 4);
  bf16x8 v;
  v[0] = (bf16_t)u0.x; v[1] = (bf16_t)u0.y; v[2] = (bf16_t)u0.z; v[3] = (bf16_t)u0.w;
  v[4] = (bf16_t)u1.x; v[5] = (bf16_t)u1.y; v[6] = (bf16_t)u1.z; v[7] = (bf16_t)u1.w;
  *(bf16x8*)d = v;
}

// ---------------- fused GEMM ----------------
// C[m][n] = sum_k A[m][k] * Bw[n][k]  (Bw row-major N x K, i.e. X @ W.T)
// Block tile: 64 rows x 512 cols, BK=32, 256 threads (4 waves),
// wave w owns cols [128w, 128w+128), all 64 rows -> 4x8 tiles of 16x16.
//
// T3 "minimum 2-phase" double-buffered pipeline (catalog recipe):
//   prologue: STAGE(buf0, t=0); barrier;
//   loop:     STAGE(buf^1, t+1)  -- DMA in flight during compute
//             ds_read + MFMA on buf
//             __syncthreads()    -- drains vmcnt(0)+lgkmcnt(0): next tile ready
//   epilogue: compute last buf (no prefetch)
// global_load_lds CANNOT be hoisted across the barrier with a single buffer
// (writes LDS directly) -- the double buffer is what restores latency hiding.
//
// LDS layout (both A and B tiles): 16-row "windows" of 1 KiB. Within a window,
// 16B slot s = r*4 + (q ^ ((r>>1)&3)) holds k-chunk q (8 bf16) of row r.
//   - staged by global_load_lds with a PRE-SWIZZLED per-lane global source
//     (linear lane->slot dest, both-sides-or-neither), 64B-coalesced per
//     4 lanes on the global side.
//   - ds_read_b128 of fragment (row=16*i+r, chunk q) hits 8 distinct
//     bank-quads per 8 lanes -> only 2-way aliasing (free). Verified round 2:
//     SQ_LDS_BANK_CONFLICT == 0.
//
// EPI 0: + bias + cell residual, LayerNorm(g,b) -> bf16 out (stride 512)
// EPI 1: + bias, exact GELU -> bf16 out (stride 1024)
// EPI 2: + bias + bf16 x residual, LayerNorm -> fp32 out (stride 512)
template <int K, int EPI>
__global__ __launch_bounds__(256, 2) void gemm_fused(
    const float* __restrict__ Af32, const bf16_t* __restrict__ Abf, const int lda,
    const bf16_t* __restrict__ Bw,
    const float* __restrict__ bias,
    const float* __restrict__ cellRes,
    const bf16_t* __restrict__ xRes,
    const float* __restrict__ gamma, const float* __restrict__ beta,
    bf16_t* __restrict__ outBf, float* __restrict__ outF32) {

  __shared__ __align__(16) bf16_t lA[2 * 64 * 32];    // 8 KiB (2 bufs x 4 windows)
  __shared__ __align__(16) bf16_t lB[2 * 512 * 32];   // 64 KiB (2 bufs x 32 windows)
  __shared__ float rs[4][64];
  __shared__ float rss[4][64];

  const int t = threadIdx.x;
  const int m0 = blockIdx.x * 64;
  const int n0 = blockIdx.y * 512;  // only nonzero for EPI==1 (N=1024)
  const int lane = t & 63;
  const int w = t >> 6;
  const int r = lane & 15;
  const int q = lane >> 4;
  const int qs = q ^ ((r >> 1) & 3);

  // LDS read bases (bf16-element units): window*512 + r*32 + qs*8
  const int aRd = r * 32 + qs * 8;
  const int bRd = w * 4096 + r * 32 + qs * 8;  // window 8w+j -> + j*512

  // staging source mapping: lane l -> (row_in_window = l>>2, chunk = (l&3)^((l>>3)&3))
  const int srow = lane >> 2;
  const int sq = (lane & 3) ^ ((lane >> 3) & 3);

  f32x4 acc[4][8];
#pragma unroll
  for (int i = 0; i < 4; ++i)
#pragma unroll
    for (int j = 0; j < 8; ++j)
#pragma unroll
      for (int p = 0; p < 4; ++p) acc[i][j][p] = 0.f;

  // EPI 0 A-staging (fp32 -> bf16 via regs): thread t handles row=t>>2, chunk c=t&3,
  // writes to the swizzled slot of window t>>6 (conflict-free ds_write_b128).
  int aWr = 0;
  if constexpr (EPI == 0) {
    const int arow = t >> 2;
    const int c = t & 3;
    const int rr = arow & 15;
    aWr = (arow >> 4) * 512 + (rr * 4 + (c ^ ((rr >> 1) & 3))) * 8;
  }

  auto stage = [&](int buf, int k0) {
    bf16_t* lBb = lB + (buf << 14);  // buf * 512*32
    bf16_t* lAb = lA + (buf << 11);  // buf * 64*32
#pragma unroll
    for (int i = 0; i < 8; ++i) {
      const bf16_t* gp = Bw + (size_t)(n0 + 64 * i + 16 * w + srow) * K + (k0 + sq * 8);
      GLOAD_LDS16(gp, &lBb[(i * 4 + w) * 512]);
    }
    if constexpr (EPI == 0) {
      const float* src = Af32 + (size_t)(m0 + (t >> 2)) * lda + (k0 + (t & 3) * 8);
      float4 u0 = *(const float4*)src;
      float4 u1 = *(const float4*)(src + 4);
      bf16x8 v;
      v[0] = (bf16_t)u0.x; v[1] = (bf16_t)u0.y; v[2] = (bf16_t)u0.z; v[3] = (bf16_t)u0.w;
      v[4] = (bf16_t)u1.x; v[5] = (bf16_t)u1.y; v[6] = (bf16_t)u1.z; v[7] = (bf16_t)u1.w;
      *(bf16x8*)&lAb[aWr] = v;
    } else {
      const bf16_t* gp = Abf + (size_t)(m0 + 16 * w + srow) * lda + (k0 + sq * 8);
      GLOAD_LDS16(gp, &lAb[w * 512]);
    }
  };

  auto compute = [&](int buf) {
    const bf16_t* lAb = lA + (buf << 11);
    const bf16_t* lBb = lB + (buf << 14);
    bf16x8 af[4];
#pragma unroll
    for (int i = 0; i < 4; ++i) af[i] = *(const bf16x8*)&lAb[i * 512 + aRd];
#pragma unroll
    for (int j = 0; j < 8; ++j) {
      bf16x8 bfv = *(const bf16x8*)&lBb[j * 512 + bRd];
#pragma unroll
      for (int i = 0; i < 4; ++i)
        acc[i][j] = __builtin_amdgcn_mfma_f32_16x16x32_bf16(af[i], bfv, acc[i][j], 0, 0, 0);
    }
  };

  constexpr int NSTEP = K / 32;
  // prologue
  stage(0, 0);
  __syncthreads();  // drains vmcnt(0)+lgkmcnt(0): tile 0 resident
  int cur = 0;
#pragma unroll 2
  for (int s = 1; s < NSTEP; ++s) {
    stage(cur ^ 1, s * 32);  // issue next-tile DMA BEFORE compute
    compute(cur);            // MFMA phase hides DMA latency
    __syncthreads();         // vmcnt(0): next tile ready; reads of cur consumed
    cur ^= 1;
  }
  compute(cur);  // last tile, no prefetch

  if constexpr (EPI == 1) {
#pragma unroll
    for (int j = 0; j < 8; ++j) {
      const int colg = n0 + 128 * w + 16 * j + r;
      const float bb = bias[colg];
#pragma unroll
      for (int i = 0; i < 4; ++i)
#pragma unroll
        for (int p = 0; p < 4; ++p) {
          const int rowg = m0 + 16 * i + 4 * q + p;
          float v = acc[i][j][p] + bb;
          float g = 0.5f * v * (1.0f + erff(v * 0.70710678118654752f));
          outBf[(size_t)rowg * 1024 + colg] = (bf16_t)g;
        }
    }
  } else {
    float s[4][4], ss[4][4];
#pragma unroll
    for (int i = 0; i < 4; ++i)
#pragma unroll
      for (int p = 0; p < 4; ++p) { s[i][p] = 0.f; ss[i][p] = 0.f; }

#pragma unroll
    for (int j = 0; j < 8; ++j) {
      const int col = 128 * w + 16 * j + r;
      const float bb = bias[col];
#pragma unroll
      for (int i = 0; i < 4; ++i)
#pragma unroll
        for (int p = 0; p < 4; ++p) {
          const int rowg = m0 + 16 * i + 4 * q + p;
          float v = acc[i][j][p] + bb;
          if constexpr (EPI == 0) v += cellRes[(size_t)rowg * 512 + col];
          else                    v += (float)xRes[(size_t)rowg * 512 + col];
          acc[i][j][p] = v;
          s[i][p] += v;
          ss[i][p] += v * v;
        }
    }
    // quad (16-lane) butterfly reduce over r
#pragma unroll
    for (int m = 1; m <= 8; m <<= 1) {
#pragma unroll
      for (int i = 0; i < 4; ++i)
#pragma unroll
        for (int p = 0; p < 4; ++p) {
          s[i][p] += __shfl_xor(s[i][p], m);
          ss[i][p] += __shfl_xor(ss[i][p], m);
        }
    }
    if (r == 0) {
#pragma unroll
      for (int i = 0; i < 4; ++i)
#pragma unroll
        for (int p = 0; p < 4; ++p) {
          rs[w][16 * i + 4 * q + p] = s[i][p];
          rss[w][16 * i + 4 * q + p] = ss[i][p];
        }
    }
    __syncthreads();
    float mu[4][4], inv[4][4];
#pragma unroll
    for (int i = 0; i < 4; ++i)
#pragma unroll
      for (int p = 0; p < 4; ++p) {
        const int rl = 16 * i + 4 * q + p;
        float tS = rs[0][rl] + rs[1][rl] + rs[2][rl] + rs[3][rl];
        float tQ = rss[0][rl] + rss[1][rl] + rss[2][rl] + rss[3][rl];
        float m_ = tS * (1.0f / 512.0f);
        float v_ = tQ * (1.0f / 512.0f) - m_ * m_;
        mu[i][p] = m_;
        inv[i][p] = rsqrtf(v_ + 1e-5f);
      }
#pragma unroll
    for (int j = 0; j < 8; ++j) {
      const int col = 128 * w + 16 * j + r;
      const float ga = gamma[col], be = beta[col];
#pragma unroll
      for (int i = 0; i < 4; ++i)
#pragma unroll
        for (int p = 0; p < 4; ++p) {
          const int rowg = m0 + 16 * i + 4 * q + p;
          float v = (acc[i][j][p] - mu[i][p]) * inv[i][p] * ga + be;
          if constexpr (EPI == 0) outBf[(size_t)rowg * 512 + col] = (bf16_t)v;
          else                    outF32[(size_t)rowg * 512 + col] = v;
        }
    }
  }
}

extern "C" void kernel_launch(void* const* d_in, const int* in_sizes, int n_in,
                              void* d_out, int out_size, void* d_ws, size_t ws_size,
                              hipStream_t stream) {
  const float* cell = (const float*)d_in[0];
  const float* pert = (const float*)d_in[1];
  const float* Wp   = (const float*)d_in[2];
  const float* bp   = (const float*)d_in[3];
  // d_in[4..7] = Wq,bq,Wk,bk: dead (softmax over a single key == 1 -> attn = v)
  const float* Wv   = (const float*)d_in[8];
  const float* bv   = (const float*)d_in[9];
  const float* Wo   = (const float*)d_in[10];
  const float* bo   = (const float*)d_in[11];
  const float* g1   = (const float*)d_in[12];
  const float* be1  = (const float*)d_in[13];
  const float* g2   = (const float*)d_in[14];
  const float* be2  = (const float*)d_in[15];
  const float* W1   = (const float*)d_in[16];
  const float* b1   = (const float*)d_in[17];
  const float* W2   = (const float*)d_in[18];
  const float* b2   = (const float*)d_in[19];

  char* ws = (char*)d_ws;
  float*  Wvp   = (float*)(ws + 0);          // 512*256*4   = 524288
  float*  bvp   = (float*)(ws + 524288);     // 512*4 (pad) = 2048
  float*  bcomb = (float*)(ws + 526336);     // 512*4 (pad) = 2048
  bf16_t* Wc    = (bf16_t*)(ws + 528384);    // 512*256*2   = 262144
  bf16_t* W1b   = (bf16_t*)(ws + 790528);    // 1024*512*2  = 1048576
  bf16_t* W2b   = (bf16_t*)(ws + 1839104);   // 512*1024*2  = 1048576
  bf16_t* xws   = (bf16_t*)(ws + 2887680);   // 65536*512*2 = 67108864
  bf16_t* hws   = (bf16_t*)(ws + 69996544);  // 65536*1024*2 = 134217728
  (void)in_sizes; (void)n_in; (void)out_size; (void)ws_size;

  prep_wvp<<<512, 256, 0, stream>>>(Wv, Wp, bp, bv, Wvp, bvp);
  prep_wc<<<512, 256, 0, stream>>>(Wo, bo, Wvp, bvp, Wc, bcomb);
  prep_cast<<<512, 256, 0, stream>>>(W1, W2, W1b, W2b);

  // G1: attn (pert @ Wc.T + bcomb) + cell residual + LN1 -> x bf16
  gemm_fused<256, 0><<<dim3(1024, 1), 256, 0, stream>>>(
      pert, nullptr, 256, Wc, bcomb, cell, nullptr, g1, be1, xws, nullptr);
  // G2: h = gelu(x @ W1.T + b1) -> bf16
  gemm_fused<512, 1><<<dim3(1024, 2), 256, 0, stream>>>(
      nullptr, xws, 512, W1b, b1, nullptr, nullptr, nullptr, nullptr, hws, nullptr);
  // G3: out = LN2(x + h @ W2.T + b2) -> fp32
  gemm_fused<1024, 2><<<dim3(1024, 1), 256, 0, stream>>>(
      nullptr, hws, 1024, W2b, b2, nullptr, xws, g2, be2, nullptr, (float*)d_out);
}